// Round 6
// baseline (160.321 us; speedup 1.0000x reference)
//
#include <hip/hip_runtime.h>
#include <hip/hip_bf16.h>

typedef __bf16    bf16x8  __attribute__((ext_vector_type(8)));
typedef __bf16    bf16x4  __attribute__((ext_vector_type(4)));
typedef _Float16  half8   __attribute__((ext_vector_type(8)));
typedef _Float16  half4   __attribute__((ext_vector_type(4)));
typedef float     floatx4 __attribute__((ext_vector_type(4)));

constexpr int Bc  = 2;
constexpr int Hc  = 16;
constexpr int Lc  = 2048;
constexpr int Dc  = 64;
constexpr int BHn = Bc * Hc;     // 32
constexpr int BM  = 128;         // query rows per block (2 strips of 16 per wave)
constexpr int BN  = 64;          // keys per tile
constexpr int NQT = Lc / BM;     // 16 query tiles
constexpr int LDP = 72;          // padded LDS row stride: 144 B rows, 16B-aligned, <=2-way conflicts
constexpr int BUFB = BN * LDP * 2 + Dc * LDP * 2;   // 18432 B per double-buffer slot

// ---- fused pre-pass: K fp32->bf16, V fp32 -> fp16 transposed+key-permuted ----
__global__ void prep(const float* __restrict__ kp, const float* __restrict__ vp,
                     __bf16* __restrict__ k16, _Float16* __restrict__ v16) {
    const int bid = blockIdx.x, tid = threadIdx.x;
    if (bid < 1024) {
        const size_t base = (size_t)bid * 4096 + tid * 4;
        #pragma unroll
        for (int rep = 0; rep < 4; ++rep) {
            const size_t i = base + rep * 1024;
            floatx4 v = *(const floatx4*)(kp + i);
            bf16x4 b;
            b[0] = (__bf16)v[0]; b[1] = (__bf16)v[1]; b[2] = (__bf16)v[2]; b[3] = (__bf16)v[3];
            *(bf16x4*)(k16 + i) = b;
        }
    } else {
        const int vb  = bid - 1024;
        const int bh  = vb >> 5, kt = vb & 31;
        const int key = kt * 64 + (tid & 63);
        const int k5  = key & 31;
        const int pcol = (key & ~31) | (((k5 >> 2) & 3) * 8 + ((k5 >> 4) & 1) * 4 + (k5 & 3));
        const int d0  = (tid >> 6) * 16;
        const float* src = vp + ((size_t)bh * Lc + key) * Dc;
        _Float16*    dst = v16 + (size_t)bh * Dc * Lc + pcol;
        #pragma unroll
        for (int i = 0; i < 16; ++i) {
            const int d = d0 + i;
            dst[(size_t)d * Lc] = (_Float16)src[d];
        }
    }
}

// ================= common inner body (templated on epilogue) =================
// Computes the flash loop for q-tile qi over KV tiles [j0, j1], accumulating
// oacc (O^T partials, C-layout) and zacc. Verified layout math from R3-R5.
struct LoopOut { floatx4 oacc[2][4]; float z[2]; };

__device__ __forceinline__ void flash_loop(
    const float* __restrict__ qbase, const __bf16* __restrict__ kbase,
    const _Float16* __restrict__ vbase, unsigned char* smem,
    int q0, int j0, int j1, int tid, LoopOut& R)
{
    const int wv   = tid >> 6;
    const int lane = tid & 63;
    const int lm   = lane & 15;
    const int quad = lane >> 4;
    const int gr = tid >> 3;          // granule row 0..31
    const int gc = (tid & 7) * 8;     // granule col (elements)

    // prefetch tile j0 (in flight during Q staging)
    bf16x8 kr[2]; half8 vr[2];
    {
        const __bf16*   kt0 = kbase + (size_t)j0 * BN * Dc;
        const _Float16* vt0 = vbase + (size_t)j0 * BN;
        kr[0] = *(const bf16x8*)(kt0 + 8 * tid);
        kr[1] = *(const bf16x8*)(kt0 + 8 * (tid + 256));
        vr[0] = *(const half8*)(vt0 + (size_t)gr * Lc + gc);
        vr[1] = *(const half8*)(vt0 + (size_t)(gr + 32) * Lc + gc);
    }

    // stage Q (fp32 -> bf16), extract per-strip B-frags
    {
        __bf16* Qs = (__bf16*)smem;
        const int r0 = tid >> 4, c4 = tid & 15;
        #pragma unroll
        for (int rep = 0; rep < 8; ++rep) {
            const int row = r0 + rep * 16;
            floatx4 v = *(const floatx4*)(qbase + row * Dc + c4 * 4);
            bf16x4 b;
            b[0] = (__bf16)v[0]; b[1] = (__bf16)v[1]; b[2] = (__bf16)v[2]; b[3] = (__bf16)v[3];
            *(bf16x4*)&Qs[row * LDP + c4 * 4] = b;
        }
    }
    __syncthreads();
    bf16x8 qa[2][2];
    {
        __bf16* Qs = (__bf16*)smem;
        #pragma unroll
        for (int st = 0; st < 2; ++st)
            #pragma unroll
            for (int kf = 0; kf < 2; ++kf)
                qa[st][kf] = *(const bf16x8*)&Qs[(32 * wv + 16 * st + lm) * LDP + kf * 32 + quad * 8];
    }
    __syncthreads();

    #pragma unroll
    for (int st = 0; st < 2; ++st) {
        R.z[st] = 0.f;
        #pragma unroll
        for (int db = 0; db < 4; ++db) R.oacc[st][db] = floatx4{0.f, 0.f, 0.f, 0.f};
    }

    for (int j = j0; j <= j1; ++j) {
        __bf16*   Ks = (__bf16*)(smem + (j & 1) * BUFB);
        _Float16* VT = (_Float16*)(smem + (j & 1) * BUFB + BN * LDP * 2);

        *(bf16x8*)&Ks[gr * LDP + gc]        = kr[0];
        *(bf16x8*)&Ks[(gr + 32) * LDP + gc] = kr[1];
        *(half8*)&VT[gr * LDP + gc]         = vr[0];
        *(half8*)&VT[(gr + 32) * LDP + gc]  = vr[1];

        __syncthreads();

        if (j < j1) {   // next tile's loads stay in flight across this iteration's compute
            const __bf16*   ktn = kbase + (size_t)(j + 1) * BN * Dc;
            const _Float16* vtn = vbase + (size_t)(j + 1) * BN;
            kr[0] = *(const bf16x8*)(ktn + 8 * tid);
            kr[1] = *(const bf16x8*)(ktn + 8 * (tid + 256));
            vr[0] = *(const half8*)(vtn + (size_t)gr * Lc + gc);
            vr[1] = *(const half8*)(vtn + (size_t)(gr + 32) * Lc + gc);
        }

        const int  slo0  = q0 + 32 * wv;
        const bool live0 = (j * BN <= slo0 + 15);
        const bool live1 = (j * BN <= slo0 + 31);

        // S^T = K * Q^T
        floatx4 sacc[2][4] = {};
        #pragma unroll
        for (int kb = 0; kb < 4; ++kb)
            #pragma unroll
            for (int kf = 0; kf < 2; ++kf) {
                bf16x8 ka = *(const bf16x8*)&Ks[(16 * kb + lm) * LDP + kf * 32 + quad * 8];
                if (live0) sacc[0][kb] = __builtin_amdgcn_mfma_f32_16x16x32_bf16(ka, qa[0][kf], sacc[0][kb], 0, 0, 0);
                if (live1) sacc[1][kb] = __builtin_amdgcn_mfma_f32_16x16x32_bf16(ka, qa[1][kf], sacc[1][kb], 0, 0, 0);
            }

        // Taylor + causal mask + z; pack W as half8 B-frags
        half8 wf[2][2];
        const bool live[2] = {live0, live1};
        #pragma unroll
        for (int st = 0; st < 2; ++st) {
            if (!live[st]) continue;
            const int  strip_lo = slo0 + 16 * st;
            const bool nm   = (j * BN + 63 > strip_lo);
            const int  qrow = strip_lo + lm;
            #pragma unroll
            for (int kb = 0; kb < 4; ++kb) {
                #pragma unroll
                for (int r = 0; r < 4; ++r) {
                    const float a = __builtin_fmaf(sacc[st][kb][r], 0.125f, 1.0f);
                    float w = __builtin_fmaf(a, 0.5f * a, 0.5f);
                    if (nm) {
                        const int key = j * BN + 16 * kb + 4 * quad + r;
                        w = (key <= qrow) ? w : 0.0f;
                    }
                    R.z[st] += w;
                    wf[st][kb >> 1][(kb & 1) * 4 + r] = (_Float16)w;
                }
            }
        }

        // O^T += V^T * W^T (K=32 f16, permuted V^T b128 frags)
        #pragma unroll
        for (int db = 0; db < 4; ++db)
            #pragma unroll
            for (int grp = 0; grp < 2; ++grp) {
                half8 va = *(const half8*)&VT[(16 * db + lm) * LDP + 32 * grp + 8 * quad];
                if (live0) R.oacc[0][db] = __builtin_amdgcn_mfma_f32_16x16x32_f16(va, wf[0][grp], R.oacc[0][db], 0, 0, 0);
                if (live1) R.oacc[1][db] = __builtin_amdgcn_mfma_f32_16x16x32_f16(va, wf[1][grp], R.oacc[1][db], 0, 0, 0);
            }
    }
}

// ================= split kernel: 1024 blocks, 4/CU, writes partials =================
__global__ __launch_bounds__(256, 4)
void taylor_attn_split(const float* __restrict__ qp, const __bf16* __restrict__ k16,
                       const _Float16* __restrict__ v16,
                       float* __restrict__ O0, float* __restrict__ O1,
                       float* __restrict__ z0, float* __restrict__ z1)
{
    alignas(16) __shared__ unsigned char smem[2 * BUFB];   // 36864 B -> 4 blocks/CU

    const int tid  = threadIdx.x;
    const int g    = (int)(blockIdx.x >> 8);        // round 0..3
    const int p    = (int)((blockIdx.x >> 6) & 3);  // position-in-round 0..3
    const int half = (int)((blockIdx.x >> 5) & 1);
    const int bh   = (int)(blockIdx.x & 31);
    // alternate orientation per round so per-CU iter sums are constant (34)
    const int qi   = (g == 0) ? (15 - p) : (g == 1) ? (8 + p) : (g == 2) ? (7 - p) : p;
    const int q0   = qi * BM;
    const int j0   = half ? (qi + 1) : 0;
    const int j1   = half ? (2 * qi + 1) : qi;

    LoopOut R;
    flash_loop(qp + ((size_t)bh * Lc + q0) * Dc,
               k16 + (size_t)bh * Lc * Dc,
               v16 + (size_t)bh * Dc * Lc,
               smem, q0, j0, j1, tid, R);

    float* Op = half ? O1 : O0;
    float* zp = half ? z1 : z0;
    const int lane = tid & 63, lm = lane & 15, quad = lane >> 4, wv = tid >> 6;
    #pragma unroll
    for (int st = 0; st < 2; ++st) {
        float z = R.z[st];
        z += __shfl_xor(z, 16);
        z += __shfl_xor(z, 32);
        const int qrow = q0 + 32 * wv + 16 * st + lm;
        float* orow = Op + ((size_t)bh * Lc + qrow) * Dc;
        #pragma unroll
        for (int db = 0; db < 4; ++db)
            #pragma unroll
            for (int r = 0; r < 4; ++r)
                orow[16 * db + 4 * quad + r] = R.oacc[st][db][r];
        if (quad == 0) zp[(size_t)bh * Lc + qrow] = z;
    }
}

// ================= combine: out = (O0+O1)/(z0+z1+eps) =================
__global__ void combine(const float* __restrict__ O0, const float* __restrict__ O1,
                        const float* __restrict__ z0, const float* __restrict__ z1,
                        float* __restrict__ out)
{
    const size_t e = ((size_t)blockIdx.x * 256 + threadIdx.x) * 4;
    const size_t row = e >> 6;
    const float inv = 1.0f / (z0[row] + z1[row] + 1e-6f);
    floatx4 a = *(const floatx4*)(O0 + e);
    floatx4 b = *(const floatx4*)(O1 + e);
    floatx4 r;
    r[0] = (a[0] + b[0]) * inv; r[1] = (a[1] + b[1]) * inv;
    r[2] = (a[2] + b[2]) * inv; r[3] = (a[3] + b[3]) * inv;
    *(floatx4*)(out + e) = r;
}

// ================= fallback (R5 path): 512 blocks, normalizes in-kernel =================
__global__ __launch_bounds__(256, 2)
void taylor_attn(const float* __restrict__ qp, const __bf16* __restrict__ k16,
                 const _Float16* __restrict__ v16, float* __restrict__ op)
{
    alignas(16) __shared__ unsigned char smem[2 * BUFB];
    const int tid   = threadIdx.x;
    const int cu    = (int)(blockIdx.x & 255);
    const int snd   = (int)(blockIdx.x >> 8);
    const int bh    = cu & 31;
    const int qslot = cu >> 5;
    const int qi    = snd ? qslot : (NQT - 1 - qslot);
    const int q0    = qi * BM;

    LoopOut R;
    flash_loop(qp + ((size_t)bh * Lc + q0) * Dc,
               k16 + (size_t)bh * Lc * Dc,
               v16 + (size_t)bh * Dc * Lc,
               smem, q0, 0, 2 * qi + 1, tid, R);

    const int lane = tid & 63, lm = lane & 15, quad = lane >> 4, wv = tid >> 6;
    #pragma unroll
    for (int st = 0; st < 2; ++st) {
        float z = R.z[st];
        z += __shfl_xor(z, 16);
        z += __shfl_xor(z, 32);
        const float inv = 1.0f / (z + 1e-6f);
        const int qrow = q0 + 32 * wv + 16 * st + lm;
        float* orow = op + ((size_t)bh * Lc + qrow) * Dc;
        #pragma unroll
        for (int db = 0; db < 4; ++db)
            #pragma unroll
            for (int r = 0; r < 4; ++r)
                orow[16 * db + 4 * quad + r] = R.oacc[st][db][r] * inv;
    }
}

extern "C" void kernel_launch(void* const* d_in, const int* in_sizes, int n_in,
                              void* d_out, int out_size, void* d_ws, size_t ws_size,
                              hipStream_t stream) {
    const float* q = (const float*)d_in[0];
    const float* k = (const float*)d_in[1];
    const float* v = (const float*)d_in[2];
    float* o = (float*)d_out;

    char* ws = (char*)d_ws;
    constexpr size_t SZ_KV = (size_t)BHn * Lc * Dc * 2;      // 8 MB each
    constexpr size_t SZ_O  = (size_t)BHn * Lc * Dc * 4;      // 16 MB each
    constexpr size_t SZ_Z  = (size_t)BHn * Lc * 4;           // 256 KB each
    __bf16*   k16 = (__bf16*)ws;
    _Float16* v16 = (_Float16*)(ws + SZ_KV);
    float* O0 = (float*)(ws + 2 * SZ_KV);
    float* O1 = (float*)(ws + 2 * SZ_KV + SZ_O);
    float* z0 = (float*)(ws + 2 * SZ_KV + 2 * SZ_O);
    float* z1 = (float*)(ws + 2 * SZ_KV + 2 * SZ_O + SZ_Z);
    const size_t need = 2 * SZ_KV + 2 * SZ_O + 2 * SZ_Z;     // ~50.9 MB

    prep<<<dim3(2048), dim3(256), 0, stream>>>(k, v, k16, v16);
    if (ws_size >= need) {
        taylor_attn_split<<<dim3(1024), dim3(256), 0, stream>>>(q, k16, v16, O0, O1, z0, z1);
        combine<<<dim3((BHn * Lc * Dc) / (256 * 4)), dim3(256), 0, stream>>>(O0, O1, z0, z1, o);
    } else {
        taylor_attn<<<dim3(NQT * BHn), dim3(256), 0, stream>>>(q, k16, v16, o);
    }
}

// Round 8
// 123.545 us; speedup vs baseline: 1.2977x; 1.2977x over previous
//
#include <hip/hip_runtime.h>
#include <hip/hip_bf16.h>

typedef __bf16    bf16x8  __attribute__((ext_vector_type(8)));
typedef __bf16    bf16x4  __attribute__((ext_vector_type(4)));
typedef _Float16  half8   __attribute__((ext_vector_type(8)));
typedef _Float16  half4   __attribute__((ext_vector_type(4)));
typedef _Float16  half2   __attribute__((ext_vector_type(2)));
typedef float     floatx4 __attribute__((ext_vector_type(4)));

constexpr int Bc  = 2;
constexpr int Hc  = 16;
constexpr int Lc  = 2048;
constexpr int Dc  = 64;
constexpr int BHn = Bc * Hc;     // 32
constexpr int BM  = 128;         // query rows per block (2 strips of 16 per wave)
constexpr int BN  = 64;          // keys per tile
constexpr int NQT = Lc / BM;     // 16 query tiles
constexpr int LDP = 72;          // padded LDS row stride: 144 B rows, 16B-aligned, <=2-way conflicts
constexpr int BUFB = BN * LDP * 2 + Dc * LDP * 2;   // 18432 B per double-buffer slot

static __device__ __forceinline__ half2 pack_f16(float a, float b) {
    return __builtin_bit_cast(half2, __builtin_amdgcn_cvt_pkrtz(a, b));
}

// ---- fused pre-pass: K fp32->bf16, V fp32 -> fp16 transposed+key-permuted ----
// V^T layout: [bh][d][pcol]; within each 32-key group key k5 -> column 8*((k5>>2)&3)+4*(k5>>4)+(k5&3)
// so PV A-frags (k=quad*8+j) read b128-contiguous and register W B-frags pack as half8.
__global__ void prep(const float* __restrict__ kp, const float* __restrict__ vp,
                     __bf16* __restrict__ k16, _Float16* __restrict__ v16) {
    const int bid = blockIdx.x, tid = threadIdx.x;
    if (bid < 1024) {
        const size_t base = (size_t)bid * 4096 + tid * 4;
        #pragma unroll
        for (int rep = 0; rep < 4; ++rep) {
            const size_t i = base + rep * 1024;
            floatx4 v = *(const floatx4*)(kp + i);
            bf16x4 b;
            b[0] = (__bf16)v[0]; b[1] = (__bf16)v[1]; b[2] = (__bf16)v[2]; b[3] = (__bf16)v[3];
            *(bf16x4*)(k16 + i) = b;
        }
    } else {
        const int vb  = bid - 1024;
        const int bh  = vb >> 5, kt = vb & 31;
        const int key = kt * 64 + (tid & 63);
        const int k5  = key & 31;
        const int pcol = (key & ~31) | (((k5 >> 2) & 3) * 8 + ((k5 >> 4) & 1) * 4 + (k5 & 3));
        const int d0  = (tid >> 6) * 16;
        const float* src = vp + ((size_t)bh * Lc + key) * Dc;
        _Float16*    dst = v16 + (size_t)bh * Dc * Lc + pcol;
        #pragma unroll
        for (int i = 0; i < 16; ++i) {
            const int d = d0 + i;
            dst[(size_t)d * Lc] = (_Float16)src[d];
        }
    }
}

// ---- main kernel: 512 blocks, complement-paired, direct store ----
__global__ __launch_bounds__(256, 2)
void taylor_attn(const float* __restrict__ qp, const __bf16* __restrict__ k16,
                 const _Float16* __restrict__ v16, float* __restrict__ op)
{
    alignas(16) __shared__ unsigned char smem[2 * BUFB];   // 36864 B: double-buffered {Ks, VT}

    const int tid  = threadIdx.x;
    const int wv   = tid >> 6;
    const int lane = tid & 63;
    const int lm   = lane & 15;
    const int quad = lane >> 4;

    const int cu    = (int)(blockIdx.x & 255);
    const int snd   = (int)(blockIdx.x >> 8);
    const int bh    = cu & 31;
    const int qslot = cu >> 5;
    const int qi    = snd ? qslot : (NQT - 1 - qslot);   // heavy tiles in the first 256
    const int q0    = qi * BM;
    const int jmax  = 2 * qi + 1;

    const float*    qbase = qp  + ((size_t)bh * Lc + q0) * Dc;
    const __bf16*   kbase = k16 + (size_t)bh * Lc * Dc;
    const _Float16* vbase = v16 + (size_t)bh * Dc * Lc;

    const int gr = tid >> 3;          // granule row 0..31
    const int gc = (tid & 7) * 8;     // granule col (elements)

    // ---- prefetch tile 0 into registers (in flight during Q staging) ----
    bf16x8 kr[2]; half8 vr[2];
    const __bf16*   kj = kbase;       // pointer-bumped per iteration
    const _Float16* vj = vbase;
    kr[0] = *(const bf16x8*)(kj + 8 * tid);
    kr[1] = *(const bf16x8*)(kj + 8 * (tid + 256));
    vr[0] = *(const half8*)(vj + (size_t)gr * Lc + gc);
    vr[1] = *(const half8*)(vj + (size_t)(gr + 32) * Lc + gc);

    // ---- stage Q (fp32 -> bf16), extract per-strip B-frags ----
    {
        __bf16* Qs = (__bf16*)smem;
        const int r0 = tid >> 4, c4 = tid & 15;
        #pragma unroll
        for (int rep = 0; rep < 8; ++rep) {
            const int row = r0 + rep * 16;
            floatx4 v = *(const floatx4*)(qbase + row * Dc + c4 * 4);
            bf16x4 b;
            b[0] = (__bf16)v[0]; b[1] = (__bf16)v[1]; b[2] = (__bf16)v[2]; b[3] = (__bf16)v[3];
            *(bf16x4*)&Qs[row * LDP + c4 * 4] = b;
        }
    }
    __syncthreads();
    bf16x8 qa[2][2];   // [strip][kf]; B-frag: n=lm (qrow), k=kf*32+quad*8+j
    {
        __bf16* Qs = (__bf16*)smem;
        #pragma unroll
        for (int st = 0; st < 2; ++st)
            #pragma unroll
            for (int kf = 0; kf < 2; ++kf)
                qa[st][kf] = *(const bf16x8*)&Qs[(32 * wv + 16 * st + lm) * LDP + kf * 32 + quad * 8];
    }
    __syncthreads();

    floatx4 oacc[2][4] = {};     // O^T accum: [strip][d-block]; col=qrow=lm, row=d=quad*4+r
    floatx4 zacc[2]    = {};     // z via ones-MFMA: every element = z[qrow=lm]

    const half8 ones = {(_Float16)1.f, (_Float16)1.f, (_Float16)1.f, (_Float16)1.f,
                        (_Float16)1.f, (_Float16)1.f, (_Float16)1.f, (_Float16)1.f};
    const half2 c8  = {(_Float16)0.125f, (_Float16)0.125f};
    const half2 c1  = {(_Float16)1.f,    (_Float16)1.f};
    const half2 ch  = {(_Float16)0.5f,   (_Float16)0.5f};

    for (int j = 0; j <= jmax; ++j) {
        __bf16*   Ks = (__bf16*)(smem + (j & 1) * BUFB);
        _Float16* VT = (_Float16*)(smem + (j & 1) * BUFB + BN * LDP * 2);

        // ---- write the prefetched tile into this iteration's buffer ----
        *(bf16x8*)&Ks[gr * LDP + gc]        = kr[0];
        *(bf16x8*)&Ks[(gr + 32) * LDP + gc] = kr[1];
        *(half8*)&VT[gr * LDP + gc]         = vr[0];
        *(half8*)&VT[(gr + 32) * LDP + gc]  = vr[1];

        __syncthreads();

        // ---- next tile's loads issued here; consumed at next iteration's LDS write ----
        if (j < jmax) {
            kj += BN * Dc;
            vj += BN;
            kr[0] = *(const bf16x8*)(kj + 8 * tid);
            kr[1] = *(const bf16x8*)(kj + 8 * (tid + 256));
            vr[0] = *(const half8*)(vj + (size_t)gr * Lc + gc);
            vr[1] = *(const half8*)(vj + (size_t)(gr + 32) * Lc + gc);
        }

        // ---- S^T = K * Q^T : D[key][qrow]; K-frags shared by both strips ----
        floatx4 sacc[2][4] = {};
        #pragma unroll
        for (int kb = 0; kb < 4; ++kb)
            #pragma unroll
            for (int kf = 0; kf < 2; ++kf) {
                bf16x8 ka = *(const bf16x8*)&Ks[(16 * kb + lm) * LDP + kf * 32 + quad * 8];
                sacc[0][kb] = __builtin_amdgcn_mfma_f32_16x16x32_bf16(ka, qa[0][kf], sacc[0][kb], 0, 0, 0);
                sacc[1][kb] = __builtin_amdgcn_mfma_f32_16x16x32_bf16(ka, qa[1][kf], sacc[1][kb], 0, 0, 0);
            }

        // ---- packed-f16 Taylor + causal mask; wf = W B-frags (registers only) ----
        half8 wf[2][2];
        #pragma unroll
        for (int st = 0; st < 2; ++st) {
            const int  strip_lo = q0 + 32 * wv + 16 * st;
            const bool nm  = (j * BN + 63 > strip_lo);   // any masked key in this tile?
            const int  thr = strip_lo + lm - j * BN;     // key-index threshold (may be <0)
            half2 wh[4][2];                              // [kb][pair]
            #pragma unroll
            for (int kb = 0; kb < 4; ++kb) {
                half2 s01 = pack_f16(sacc[st][kb][0], sacc[st][kb][1]);
                half2 s23 = pack_f16(sacc[st][kb][2], sacc[st][kb][3]);
                half2 a01 = s01 * c8 + c1;               // fuses to v_pk_fma_f16
                half2 a23 = s23 * c8 + c1;
                half2 w01 = a01 * (a01 * ch) + ch;       // 0.5*a^2 + 0.5
                half2 w23 = a23 * (a23 * ch) + ch;
                if (nm) {
                    const int i0 = 16 * kb + 4 * quad;
                    w01[0] = (i0 + 0 <= thr) ? w01[0] : (_Float16)0.f;
                    w01[1] = (i0 + 1 <= thr) ? w01[1] : (_Float16)0.f;
                    w23[0] = (i0 + 2 <= thr) ? w23[0] : (_Float16)0.f;
                    w23[1] = (i0 + 3 <= thr) ? w23[1] : (_Float16)0.f;
                }
                wh[kb][0] = w01;
                wh[kb][1] = w23;
            }
            #pragma unroll
            for (int grp = 0; grp < 2; ++grp) {
                half4 lo = __builtin_shufflevector(wh[2 * grp][0],     wh[2 * grp][1],     0, 1, 2, 3);
                half4 hi = __builtin_shufflevector(wh[2 * grp + 1][0], wh[2 * grp + 1][1], 0, 1, 2, 3);
                wf[st][grp] = __builtin_shufflevector(lo, hi, 0, 1, 2, 3, 4, 5, 6, 7);
            }
        }

        // ---- O^T += V^T * W^T (K=32 f16); z += 1 * W^T (ones-MFMA) ----
        #pragma unroll
        for (int db = 0; db < 4; ++db)
            #pragma unroll
            for (int grp = 0; grp < 2; ++grp) {
                half8 va = *(const half8*)&VT[(16 * db + lm) * LDP + 32 * grp + 8 * quad];
                oacc[0][db] = __builtin_amdgcn_mfma_f32_16x16x32_f16(va, wf[0][grp], oacc[0][db], 0, 0, 0);
                oacc[1][db] = __builtin_amdgcn_mfma_f32_16x16x32_f16(va, wf[1][grp], oacc[1][db], 0, 0, 0);
            }
        #pragma unroll
        for (int grp = 0; grp < 2; ++grp) {
            zacc[0] = __builtin_amdgcn_mfma_f32_16x16x32_f16(ones, wf[0][grp], zacc[0], 0, 0, 0);
            zacc[1] = __builtin_amdgcn_mfma_f32_16x16x32_f16(ones, wf[1][grp], zacc[1], 0, 0, 0);
        }
    }

    // ---- finalize: z already per-column in every lane; normalize, store ----
    #pragma unroll
    for (int st = 0; st < 2; ++st) {
        const float inv = 1.0f / (zacc[st][0] + 1e-6f);
        const int qrow = q0 + 32 * wv + 16 * st + lm;
        float* orow = op + ((size_t)bh * Lc + qrow) * Dc;
        #pragma unroll
        for (int db = 0; db < 4; ++db)
            #pragma unroll
            for (int r = 0; r < 4; ++r)
                orow[16 * db + 4 * quad + r] = oacc[st][db][r] * inv;
    }
}

extern "C" void kernel_launch(void* const* d_in, const int* in_sizes, int n_in,
                              void* d_out, int out_size, void* d_ws, size_t ws_size,
                              hipStream_t stream) {
    const float* q = (const float*)d_in[0];
    const float* k = (const float*)d_in[1];
    const float* v = (const float*)d_in[2];
    float* o = (float*)d_out;

    __bf16*   k16 = (__bf16*)d_ws;                                        // 8 MB
    _Float16* v16 = (_Float16*)((char*)d_ws + (size_t)BHn * Lc * Dc * 2); // 8 MB

    prep<<<dim3(2048), dim3(256), 0, stream>>>(k, v, k16, v16);
    taylor_attn<<<dim3(NQT * BHn), dim3(256), 0, stream>>>(q, k16, v16, o);
}

// Round 9
// 119.244 us; speedup vs baseline: 1.3445x; 1.0361x over previous
//
#include <hip/hip_runtime.h>
#include <hip/hip_bf16.h>

typedef __bf16    bf16x8  __attribute__((ext_vector_type(8)));
typedef __bf16    bf16x4  __attribute__((ext_vector_type(4)));
typedef _Float16  half8   __attribute__((ext_vector_type(8)));
typedef _Float16  half4   __attribute__((ext_vector_type(4)));
typedef _Float16  half2   __attribute__((ext_vector_type(2)));
typedef float     floatx4 __attribute__((ext_vector_type(4)));

constexpr int Bc  = 2;
constexpr int Hc  = 16;
constexpr int Lc  = 2048;
constexpr int Dc  = 64;
constexpr int BHn = Bc * Hc;     // 32
constexpr int BM  = 128;         // query rows per block (2 strips of 16 per wave)
constexpr int BN  = 128;         // keys per tile (halves iteration count vs BN=64)
constexpr int NQT = Lc / BM;     // 16 query tiles
constexpr int LDK = 72;          // Ks padded stride (bf16 elems)
constexpr int LDV = 136;         // VT padded stride (fp16 elems)

static __device__ __forceinline__ half2 pack_f16(float a, float b) {
    return __builtin_bit_cast(half2, __builtin_amdgcn_cvt_pkrtz(a, b));
}

// ---- fused pre-pass: K fp32->bf16, V fp32 -> fp16 transposed+key-permuted ----
// V^T layout: [bh][d][pcol]; within each 32-key group key k5 -> column 8*((k5>>2)&3)+4*(k5>>4)+(k5&3)
// so PV A-frags (k=quad*8+j) read b128-contiguous and register W B-frags pack as half8.
__global__ void prep(const float* __restrict__ kp, const float* __restrict__ vp,
                     __bf16* __restrict__ k16, _Float16* __restrict__ v16) {
    const int bid = blockIdx.x, tid = threadIdx.x;
    if (bid < 1024) {
        const size_t base = (size_t)bid * 4096 + tid * 4;
        #pragma unroll
        for (int rep = 0; rep < 4; ++rep) {
            const size_t i = base + rep * 1024;
            floatx4 v = *(const floatx4*)(kp + i);
            bf16x4 b;
            b[0] = (__bf16)v[0]; b[1] = (__bf16)v[1]; b[2] = (__bf16)v[2]; b[3] = (__bf16)v[3];
            *(bf16x4*)(k16 + i) = b;
        }
    } else {
        const int vb  = bid - 1024;
        const int bh  = vb >> 5, kt = vb & 31;
        const int key = kt * 64 + (tid & 63);
        const int k5  = key & 31;
        const int pcol = (key & ~31) | (((k5 >> 2) & 3) * 8 + ((k5 >> 4) & 1) * 4 + (k5 & 3));
        const int d0  = (tid >> 6) * 16;
        const float* src = vp + ((size_t)bh * Lc + key) * Dc;
        _Float16*    dst = v16 + (size_t)bh * Dc * Lc + pcol;
        #pragma unroll
        for (int i = 0; i < 16; ++i) {
            const int d = d0 + i;
            dst[(size_t)d * Lc] = (_Float16)src[d];
        }
    }
}

// ---- main kernel: 512 blocks, complement-paired, single LDS buffer + reg prefetch ----
__global__ __launch_bounds__(256, 2)
void taylor_attn(const float* __restrict__ qp, const __bf16* __restrict__ k16,
                 const _Float16* __restrict__ v16, float* __restrict__ op)
{
    __shared__ __bf16   Ks[BN * LDK];   // 18432 B; also used for Q staging (128 x 72)
    __shared__ _Float16 VT[Dc * LDV];   // 17408 B: V^T tile [d][pcol 0..127]

    const int tid  = threadIdx.x;
    const int wv   = tid >> 6;
    const int lane = tid & 63;
    const int lm   = lane & 15;
    const int quad = lane >> 4;

    const int cu    = (int)(blockIdx.x & 255);
    const int snd   = (int)(blockIdx.x >> 8);
    const int bh    = cu & 31;
    const int qslot = cu >> 5;
    const int qi    = snd ? qslot : (NQT - 1 - qslot);   // heavy tiles in the first 256
    const int q0    = qi * BM;
    const int jmax  = qi;                                 // BN=128: tiles 0..qi

    const float*    qbase = qp  + ((size_t)bh * Lc + q0) * Dc;
    const __bf16*   kj    = k16 + (size_t)bh * Lc * Dc;   // pointer-bumped
    const _Float16* vj    = v16 + (size_t)bh * Dc * Lc;

    // ---- prefetch tile 0 into registers (in flight during Q staging) ----
    bf16x8 kr[4]; half8 vr[4];
    #pragma unroll
    for (int rep = 0; rep < 4; ++rep)
        kr[rep] = *(const bf16x8*)(kj + 8 * (tid + 256 * rep));
    #pragma unroll
    for (int rep = 0; rep < 4; ++rep) {
        const int g = tid + 256 * rep;                    // granule: row=d (g>>4), col=(g&15)*8
        vr[rep] = *(const half8*)(vj + (size_t)(g >> 4) * Lc + (g & 15) * 8);
    }

    // ---- stage Q (fp32 -> bf16) into Ks area, extract per-strip B-frags ----
    {
        const int r0 = tid >> 4, c4 = tid & 15;
        #pragma unroll
        for (int rep = 0; rep < 8; ++rep) {
            const int row = r0 + rep * 16;
            floatx4 v = *(const floatx4*)(qbase + row * Dc + c4 * 4);
            bf16x4 b;
            b[0] = (__bf16)v[0]; b[1] = (__bf16)v[1]; b[2] = (__bf16)v[2]; b[3] = (__bf16)v[3];
            *(bf16x4*)&Ks[row * LDK + c4 * 4] = b;
        }
    }
    __syncthreads();
    bf16x8 qa[2][2];   // [strip][kf]; B-frag: n=lm (qrow), k=kf*32+quad*8+j
    #pragma unroll
    for (int st = 0; st < 2; ++st)
        #pragma unroll
        for (int kf = 0; kf < 2; ++kf)
            qa[st][kf] = *(const bf16x8*)&Ks[(32 * wv + 16 * st + lm) * LDK + kf * 32 + quad * 8];
    __syncthreads();

    floatx4 oacc[2][4] = {};     // O^T accum: [strip][d-block]; col=qrow=lm, row=d=quad*4+r
    floatx4 zacc[2]    = {};     // z via ones-MFMA: every element = z[qrow=lm]

    const half8 ones = {(_Float16)1.f, (_Float16)1.f, (_Float16)1.f, (_Float16)1.f,
                        (_Float16)1.f, (_Float16)1.f, (_Float16)1.f, (_Float16)1.f};
    const half2 c8  = {(_Float16)0.125f, (_Float16)0.125f};
    const half2 c1  = {(_Float16)1.f,    (_Float16)1.f};
    const half2 ch  = {(_Float16)0.5f,   (_Float16)0.5f};

    for (int j = 0; j <= jmax; ++j) {
        // ---- write the prefetched tile into LDS (vmcnt waits only on these regs) ----
        #pragma unroll
        for (int rep = 0; rep < 4; ++rep) {
            const int c = tid + 256 * rep;
            *(bf16x8*)&Ks[(c >> 3) * LDK + (c & 7) * 8] = kr[rep];
        }
        #pragma unroll
        for (int rep = 0; rep < 4; ++rep) {
            const int g = tid + 256 * rep;
            *(half8*)&VT[(g >> 4) * LDV + (g & 15) * 8] = vr[rep];
        }
        __syncthreads();

        // ---- issue next tile's loads: a full (double-size) compute phase to land ----
        if (j < jmax) {
            kj += BN * Dc;
            vj += BN;
            #pragma unroll
            for (int rep = 0; rep < 4; ++rep)
                kr[rep] = *(const bf16x8*)(kj + 8 * (tid + 256 * rep));
            #pragma unroll
            for (int rep = 0; rep < 4; ++rep) {
                const int g = tid + 256 * rep;
                vr[rep] = *(const half8*)(vj + (size_t)(g >> 4) * Lc + (g & 15) * 8);
            }
        }

        const bool nm = (j == jmax);                 // only the diagonal tile masks
        // ---- two key-halves of 64: S -> Taylor -> PV each ----
        #pragma unroll
        for (int half = 0; half < 2; ++half) {
            // S^T = K * Q^T for key rows [64*half, 64*half+64)
            floatx4 sacc[2][4] = {};
            #pragma unroll
            for (int kb4 = 0; kb4 < 4; ++kb4) {
                const int kb = 4 * half + kb4;
                #pragma unroll
                for (int kf = 0; kf < 2; ++kf) {
                    bf16x8 ka = *(const bf16x8*)&Ks[(16 * kb + lm) * LDK + kf * 32 + quad * 8];
                    sacc[0][kb4] = __builtin_amdgcn_mfma_f32_16x16x32_bf16(ka, qa[0][kf], sacc[0][kb4], 0, 0, 0);
                    sacc[1][kb4] = __builtin_amdgcn_mfma_f32_16x16x32_bf16(ka, qa[1][kf], sacc[1][kb4], 0, 0, 0);
                }
            }

            // packed-f16 Taylor + causal mask; wf = W B-frags (registers only)
            half8 wf[2][2];
            #pragma unroll
            for (int st = 0; st < 2; ++st) {
                const int strip_lo = q0 + 32 * wv + 16 * st;
                const int thr = strip_lo + lm - j * BN;   // key threshold within tile
                half2 wh[4][2];
                #pragma unroll
                for (int kb4 = 0; kb4 < 4; ++kb4) {
                    half2 s01 = pack_f16(sacc[st][kb4][0], sacc[st][kb4][1]);
                    half2 s23 = pack_f16(sacc[st][kb4][2], sacc[st][kb4][3]);
                    half2 a01 = s01 * c8 + c1;            // fuses to v_pk_fma_f16
                    half2 a23 = s23 * c8 + c1;
                    half2 w01 = a01 * (a01 * ch) + ch;    // 0.5*a^2 + 0.5
                    half2 w23 = a23 * (a23 * ch) + ch;
                    if (nm) {
                        const int i0 = 16 * (4 * half + kb4) + 4 * quad;
                        w01[0] = (i0 + 0 <= thr) ? w01[0] : (_Float16)0.f;
                        w01[1] = (i0 + 1 <= thr) ? w01[1] : (_Float16)0.f;
                        w23[0] = (i0 + 2 <= thr) ? w23[0] : (_Float16)0.f;
                        w23[1] = (i0 + 3 <= thr) ? w23[1] : (_Float16)0.f;
                    }
                    wh[kb4][0] = w01;
                    wh[kb4][1] = w23;
                }
                #pragma unroll
                for (int g2 = 0; g2 < 2; ++g2) {
                    half4 lo = __builtin_shufflevector(wh[2 * g2][0],     wh[2 * g2][1],     0, 1, 2, 3);
                    half4 hi = __builtin_shufflevector(wh[2 * g2 + 1][0], wh[2 * g2 + 1][1], 0, 1, 2, 3);
                    wf[st][g2] = __builtin_shufflevector(lo, hi, 0, 1, 2, 3, 4, 5, 6, 7);
                }
            }

            // O^T += V^T * W^T (K=32 f16) over this half's two 32-key groups; z via ones-MFMA
            #pragma unroll
            for (int db = 0; db < 4; ++db)
                #pragma unroll
                for (int g2 = 0; g2 < 2; ++g2) {
                    const int grp = 2 * half + g2;
                    half8 va = *(const half8*)&VT[(16 * db + lm) * LDV + 32 * grp + 8 * quad];
                    oacc[0][db] = __builtin_amdgcn_mfma_f32_16x16x32_f16(va, wf[0][g2], oacc[0][db], 0, 0, 0);
                    oacc[1][db] = __builtin_amdgcn_mfma_f32_16x16x32_f16(va, wf[1][g2], oacc[1][db], 0, 0, 0);
                }
            #pragma unroll
            for (int g2 = 0; g2 < 2; ++g2) {
                zacc[0] = __builtin_amdgcn_mfma_f32_16x16x32_f16(ones, wf[0][g2], zacc[0], 0, 0, 0);
                zacc[1] = __builtin_amdgcn_mfma_f32_16x16x32_f16(ones, wf[1][g2], zacc[1], 0, 0, 0);
            }
        }
        __syncthreads();   // all waves done reading Ks/VT before next iteration's write
    }

    // ---- finalize: z already per-column in every lane; normalize, store ----
    #pragma unroll
    for (int st = 0; st < 2; ++st) {
        const float inv = 1.0f / (zacc[st][0] + 1e-6f);
        const int qrow = q0 + 32 * wv + 16 * st + lm;
        float* orow = op + ((size_t)bh * Lc + qrow) * Dc;
        #pragma unroll
        for (int db = 0; db < 4; ++db)
            #pragma unroll
            for (int r = 0; r < 4; ++r)
                orow[16 * db + 4 * quad + r] = oacc[st][db][r] * inv;
    }
}

extern "C" void kernel_launch(void* const* d_in, const int* in_sizes, int n_in,
                              void* d_out, int out_size, void* d_ws, size_t ws_size,
                              hipStream_t stream) {
    const float* q = (const float*)d_in[0];
    const float* k = (const float*)d_in[1];
    const float* v = (const float*)d_in[2];
    float* o = (float*)d_out;

    __bf16*   k16 = (__bf16*)d_ws;                                        // 8 MB
    _Float16* v16 = (_Float16*)((char*)d_ws + (size_t)BHn * Lc * Dc * 2); // 8 MB

    prep<<<dim3(2048), dim3(256), 0, stream>>>(k, v, k16, v16);
    taylor_attn<<<dim3(NQT * BHn), dim3(256), 0, stream>>>(q, k16, v16, o);
}